// Round 9
// baseline (573.801 us; speedup 1.0000x reference)
//
#include <hip/hip_runtime.h>
#include <math.h>

#define N_NODES 100000
#define N_EDGES 1600000

typedef short short8 __attribute__((ext_vector_type(8)));
typedef float f32x4 __attribute__((ext_vector_type(4)));
typedef float f32x2 __attribute__((ext_vector_type(2)));
typedef _Float16 h2 __attribute__((ext_vector_type(2)));

// 1/sqrt(32) * log2(e)  (fold softmax scale + exp2 conversion into Q)
#define QSC 0.25503540f

#if defined(__has_builtin)
#if __has_builtin(__builtin_amdgcn_cvt_pk_f32_fp8) && __has_builtin(__builtin_amdgcn_cvt_pk_fp8_f32)
#define HAVE_FP8 1
#endif
#endif
#ifndef HAVE_FP8
#define HAVE_FP8 0
#endif

static __device__ __forceinline__ float bf2f(unsigned int u16) {
    return __uint_as_float(u16 << 16);
}
static __device__ __forceinline__ unsigned short f2bf(float f) {
    unsigned u = __float_as_uint(f);
    unsigned r = u + 0x7FFF + ((u >> 16) & 1);   // RTNE
    return (unsigned short)(r >> 16);
}
static __device__ __forceinline__ f32x2 bfpair(unsigned u) {
    f32x2 r;
    r.x = __uint_as_float(u << 16);
    r.y = __uint_as_float(u & 0xFFFF0000u);
    return r;
}

// ---------------- weight repack ----------------
__global__ void repack_kernel(const float* __restrict__ Wrel, const float* __restrict__ Wroot,
                              const float* __restrict__ Wq, const float* __restrict__ Wk,
                              const float* __restrict__ Wv, const float* __restrict__ Wsk,
                              const float* __restrict__ bq, const float* __restrict__ bk,
                              const float* __restrict__ bv, const float* __restrict__ bsk,
                              unsigned short* __restrict__ W1t, unsigned short* __restrict__ W2t,
                              float* __restrict__ bcat) {
    int idx = blockIdx.x * 256 + threadIdx.x;
    if (idx < 128 * 256) {
        int k = idx >> 8, c = idx & 255;
        float v;
        if (c < 192) { int r = c >> 6, cc = c & 63; v = Wrel[r * 8192 + k * 64 + cc]; }
        else v = Wroot[k * 64 + (c - 192)];
        W1t[c * 128 + k] = f2bf(v);
    }
    int i2 = idx - 128 * 256;
    if (i2 >= 0 && i2 < 64 * 512) {
        int k = i2 >> 9, c = i2 & 511;
        float v;
        if (c < 128) v = Wq[k * 128 + c];
        else if (c < 256) v = Wk[k * 128 + c - 128];
        else if (c < 384) v = Wv[k * 128 + c - 256];
        else v = Wsk[k * 128 + c - 384];
        W2t[c * 64 + k] = f2bf(v);
    }
    int i3 = idx - 128 * 256 - 64 * 512;
    if (i3 >= 0 && i3 < 512) {
        float v;
        if (i3 < 128) v = bq[i3];
        else if (i3 < 256) v = bk[i3 - 128];
        else if (i3 < 384) v = bv[i3 - 256];
        else v = bsk[i3 - 384];
        bcat[i3] = v;
    }
}

// ---------------- CSR build ----------------
// hist: per-(relation,dst) counts; rank packs [r:4 | rank:28]
__global__ void hist_kernel(const int* __restrict__ ei, const int* __restrict__ et,
                            int* __restrict__ cntr, unsigned* __restrict__ rank) {
    int e = blockIdx.x * 256 + threadIdx.x;
    if (e < N_EDGES) {
        int r = et[e];
        unsigned rk = (unsigned)atomicAdd(&cntr[r * N_NODES + ei[N_EDGES + e]], 1);
        rank[e] = rk | ((unsigned)r << 28);
    }
}

__global__ void scanA_kernel(const int* __restrict__ cntr, int* __restrict__ part) {
    __shared__ int wsum[4];
    int t = threadIdx.x;
    int base = blockIdx.x * 1024 + t * 4;
    int s = 0;
    for (int i = 0; i < 4; i++) {
        int idx = base + i;
        if (idx < N_NODES) s += cntr[idx] + cntr[N_NODES + idx] + cntr[2 * N_NODES + idx];
    }
    for (int off = 1; off < 64; off <<= 1) s += __shfl_xor(s, off);
    if ((t & 63) == 0) wsum[t >> 6] = s;
    __syncthreads();
    if (t == 0) part[blockIdx.x] = wsum[0] + wsum[1] + wsum[2] + wsum[3];
}

// scanC: bro[n] = {rs, rs+c0, rs+c0+c1, rs+c0+c1+c2}
__global__ void scanC_kernel(const int* __restrict__ cntr, const int* __restrict__ part,
                             uint4* __restrict__ bro) {
    __shared__ int wsum[4];
    __shared__ int ws2[4];
    int t = threadIdx.x;
    int lane = t & 63;
    int base = blockIdx.x * 1024 + t * 4;
    int c0v[4], c1v[4], c2v[4]; int tsum = 0;
    for (int i = 0; i < 4; i++) {
        int idx = base + i;
        if (idx < N_NODES) {
            c0v[i] = cntr[idx]; c1v[i] = cntr[N_NODES + idx]; c2v[i] = cntr[2 * N_NODES + idx];
        } else { c0v[i] = c1v[i] = c2v[i] = 0; }
        tsum += c0v[i] + c1v[i] + c2v[i];
    }
    int p = (t < blockIdx.x) ? part[t] : 0;
    for (int off = 1; off < 64; off <<= 1) p += __shfl_xor(p, off);
    if (lane == 0) ws2[t >> 6] = p;
    int x = tsum;
    for (int off = 1; off < 64; off <<= 1) { int y = __shfl_up(x, off); if (lane >= off) x += y; }
    if (lane == 63) wsum[t >> 6] = x;
    __syncthreads();
    if (t == 0) { int run = 0; for (int w = 0; w < 4; w++) { int tmp = wsum[w]; wsum[w] = run; run += tmp; } }
    __syncthreads();
    int bofs = ws2[0] + ws2[1] + ws2[2] + ws2[3];
    int excl = x - tsum + wsum[t >> 6] + bofs;
    for (int i = 0; i < 4; i++) {
        int idx = base + i;
        if (idx < N_NODES) {
            uint4 b;
            b.x = (unsigned)excl;
            b.y = (unsigned)(excl + c0v[i]);
            b.z = (unsigned)(excl + c0v[i] + c1v[i]);
            b.w = (unsigned)(excl + c0v[i] + c1v[i] + c2v[i]);
            bro[idx] = b;
        }
        excl += c0v[i] + c1v[i] + c2v[i];
    }
}

// scatter: no atomics — pos = bro[dst].sel(r) + rank
__global__ void scatter_kernel(const int* __restrict__ ei,
                               const uint4* __restrict__ bro, const unsigned* __restrict__ rank,
                               unsigned int* __restrict__ ep) {
    int e = blockIdx.x * 256 + threadIdx.x;
    if (e >= N_EDGES) return;
    int src = ei[e], dst = ei[N_EDGES + e];
    unsigned rkr = rank[e];
    int r = (int)(rkr >> 28);
    unsigned rk = rkr & 0x0FFFFFFFu;
    uint4 b = bro[dst];
    unsigned ofs = (r == 0) ? b.x : (r == 1) ? b.y : b.z;
    ep[ofs + rk] = ((unsigned)src << 2) | (unsigned)r;
}

// ---------------- GEMM1 (MFMA bf16): X[N,128] @ W1[128,256] -> hr_all bf16 [N][256] ----------------
__global__ __launch_bounds__(256) void gemm1_mfma(const float* __restrict__ X,
                                                  const unsigned short* __restrict__ W1t,
                                                  unsigned short* __restrict__ hr_all) {
    __shared__ unsigned short As[64][136];
    __shared__ unsigned short Bs[64][136];
    int t = threadIdx.x;
    int rb = blockIdx.x * 64;
    #pragma unroll
    for (int i = 0; i < 8; i++) {
        int lin = t + i * 256;
        int row = lin >> 5;
        int c4 = lin & 31;
        float4 v = make_float4(0.f, 0.f, 0.f, 0.f);
        int gr = rb + row;
        if (gr < N_NODES) v = *(const float4*)&X[gr * 128 + c4 * 4];
        unsigned w0 = (unsigned)f2bf(v.x) | ((unsigned)f2bf(v.y) << 16);
        unsigned w1 = (unsigned)f2bf(v.z) | ((unsigned)f2bf(v.w) << 16);
        *(uint2*)&As[row][c4 * 4] = make_uint2(w0, w1);
    }
    int w = t >> 6, l = t & 63;
    int wr = (w >> 1) * 32, wc = (w & 1) * 32;
    int lr = l & 15, lk = (l >> 4) * 8;
    int drow = (l >> 4) * 4;
    int dcol = l & 15;
    for (int cb4 = 0; cb4 < 4; cb4++) {
        int cb = cb4 * 64;
        __syncthreads();
        #pragma unroll
        for (int i = 0; i < 4; i++) {
            int lin = t + i * 256;
            int n = lin >> 4;
            int k8 = lin & 15;
            *(uint4*)&Bs[n][k8 * 8] = *(const uint4*)&W1t[(cb + n) * 128 + k8 * 8];
        }
        __syncthreads();
        f32x4 c00 = {0.f,0.f,0.f,0.f}, c01 = {0.f,0.f,0.f,0.f};
        f32x4 c10 = {0.f,0.f,0.f,0.f}, c11 = {0.f,0.f,0.f,0.f};
        #pragma unroll
        for (int kk = 0; kk < 128; kk += 32) {
            short8 a0 = *(const short8*)&As[wr + lr][kk + lk];
            short8 a1 = *(const short8*)&As[wr + 16 + lr][kk + lk];
            short8 b0 = *(const short8*)&Bs[wc + lr][kk + lk];
            short8 b1 = *(const short8*)&Bs[wc + 16 + lr][kk + lk];
            c00 = __builtin_amdgcn_mfma_f32_16x16x32_bf16(a0, b0, c00, 0, 0, 0);
            c01 = __builtin_amdgcn_mfma_f32_16x16x32_bf16(a0, b1, c01, 0, 0, 0);
            c10 = __builtin_amdgcn_mfma_f32_16x16x32_bf16(a1, b0, c10, 0, 0, 0);
            c11 = __builtin_amdgcn_mfma_f32_16x16x32_bf16(a1, b1, c11, 0, 0, 0);
        }
        f32x4 cc[2][2] = {{c00, c01}, {c10, c11}};
        #pragma unroll
        for (int i = 0; i < 2; i++)
            #pragma unroll
            for (int j = 0; j < 2; j++)
                #pragma unroll
                for (int rg = 0; rg < 4; rg++) {
                    int gr = rb + wr + i * 16 + drow + rg;
                    int gc = cb + wc + j * 16 + dcol;
                    if (gr < N_NODES) hr_all[gr * 256 + gc] = f2bf(cc[i][j][rg]);
                }
    }
}

// ---------------- RGCN aggregate: strided slots (idx = p0+slot, +=4), unroll 4 ----------------
__global__ __launch_bounds__(256) void rgcn_kernel(const unsigned short* __restrict__ hr,
                                                   const float* __restrict__ brg,
                                                   const uint4* __restrict__ bro,
                                                   const unsigned int* __restrict__ ep,
                                                   unsigned short* __restrict__ Hm) {
    int t = threadIdx.x, lane = t & 63;
    int n = blockIdx.x * 4 + (t >> 6);
    if (n >= N_NODES) return;
    int slot = lane >> 4, pos = lane & 15;
    const uint2* H2 = (const uint2*)hr;
    uint4 b = bro[n];
    int p0 = (int)b.x, p1 = (int)b.w;
    int c0 = (int)(b.y - b.x), c1 = (int)(b.z - b.y), c2 = (int)(b.w - b.z);
    float i0 = c0 ? 1.f / (float)c0 : 0.f;
    float i1 = c1 ? 1.f / (float)c1 : 0.f;
    float i2 = c2 ? 1.f / (float)c2 : 0.f;
    f32x2 a01 = {0.f, 0.f}, a23 = {0.f, 0.f};
    int idx = p0 + slot;
    while (idx + 12 < p1) {
        unsigned e0 = ep[idx], e1 = ep[idx + 4], e2 = ep[idx + 8], e3 = ep[idx + 12];
        uint2 h0 = H2[e0 * 16 + pos];
        uint2 h1 = H2[e1 * 16 + pos];
        uint2 h2v = H2[e2 * 16 + pos];
        uint2 h3 = H2[e3 * 16 + pos];
        float w0 = ((e0 & 3) == 0) ? i0 : ((e0 & 3) == 1) ? i1 : i2;
        float w1 = ((e1 & 3) == 0) ? i0 : ((e1 & 3) == 1) ? i1 : i2;
        float w2 = ((e2 & 3) == 0) ? i0 : ((e2 & 3) == 1) ? i1 : i2;
        float w3 = ((e3 & 3) == 0) ? i0 : ((e3 & 3) == 1) ? i1 : i2;
        a01 += w0 * bfpair(h0.x); a23 += w0 * bfpair(h0.y);
        a01 += w1 * bfpair(h1.x); a23 += w1 * bfpair(h1.y);
        a01 += w2 * bfpair(h2v.x); a23 += w2 * bfpair(h2v.y);
        a01 += w3 * bfpair(h3.x); a23 += w3 * bfpair(h3.y);
        idx += 16;
    }
    while (idx < p1) {
        unsigned e0 = ep[idx];
        uint2 h0 = H2[e0 * 16 + pos];
        float w0 = ((e0 & 3) == 0) ? i0 : ((e0 & 3) == 1) ? i1 : i2;
        a01 += w0 * bfpair(h0.x); a23 += w0 * bfpair(h0.y);
        idx += 4;
    }
    a01.x += __shfl_xor(a01.x, 16); a01.x += __shfl_xor(a01.x, 32);
    a01.y += __shfl_xor(a01.y, 16); a01.y += __shfl_xor(a01.y, 32);
    a23.x += __shfl_xor(a23.x, 16); a23.x += __shfl_xor(a23.x, 32);
    a23.y += __shfl_xor(a23.y, 16); a23.y += __shfl_xor(a23.y, 32);
    uint2 rt = H2[(n * 4 + 3) * 16 + pos];   // root block
    f32x2 r01 = bfpair(rt.x), r23 = bfpair(rt.y);
    float4 bb = ((const float4*)brg)[pos];
    float h0 = fmaxf(r01.x + bb.x + a01.x, 0.f);
    float h1 = fmaxf(r01.y + bb.y + a01.y, 0.f);
    float h2s = fmaxf(r23.x + bb.z + a23.x, 0.f);
    float h3 = fmaxf(r23.y + bb.w + a23.y, 0.f);
    if (slot == 0) {
        uint2 wv;
        wv.x = (unsigned)f2bf(h0) | ((unsigned)f2bf(h1) << 16);
        wv.y = (unsigned)f2bf(h2s) | ((unsigned)f2bf(h3) << 16);
        ((uint2*)Hm)[n * 16 + pos] = wv;
    }
}

// ---------------- GEMM2 (MFMA bf16): Hm[N,64] @ W2[64,512] + bcat ----------------
// QS fp16 row: [Q(128, pre-scaled by QSC) | skip(128)]
// KV: fp8 row [K|V] (256 B) if HAVE_FP8, else fp16 row [K|V] (512 B)
__global__ __launch_bounds__(256) void gemm2_mfma(const unsigned short* __restrict__ Hm,
                                                  const unsigned short* __restrict__ W2t,
                                                  const float* __restrict__ bcat,
                                                  _Float16* __restrict__ QS, void* __restrict__ KVp) {
#if HAVE_FP8
    unsigned char* KV = (unsigned char*)KVp;
#else
    _Float16* KV = (_Float16*)KVp;
#endif
    __shared__ unsigned short As[64][72];
    __shared__ unsigned short Bs[64][72];
    int t = threadIdx.x;
    int rb = blockIdx.x * 64;
    #pragma unroll
    for (int i = 0; i < 2; i++) {
        int lin = t + i * 256;
        int row = lin >> 3;
        int k8 = lin & 7;
        uint4 v = make_uint4(0, 0, 0, 0);
        int gr = rb + row;
        if (gr < N_NODES) v = *(const uint4*)&Hm[gr * 64 + k8 * 8];
        *(uint4*)&As[row][k8 * 8] = v;
    }
    int w = t >> 6, l = t & 63;
    int wr = (w >> 1) * 32, wc = (w & 1) * 32;
    int lr = l & 15, lk = (l >> 4) * 8;
    int drow = (l >> 4) * 4;
    int dcol = l & 15;
    for (int cb8 = 0; cb8 < 8; cb8++) {
        int cb = cb8 * 64;
        float qsc = (cb8 < 2) ? QSC : 1.f;
        __syncthreads();
        #pragma unroll
        for (int i = 0; i < 2; i++) {
            int lin = t + i * 256;
            int n = lin >> 3;
            int k8 = lin & 7;
            *(uint4*)&Bs[n][k8 * 8] = *(const uint4*)&W2t[(cb + n) * 64 + k8 * 8];
        }
        __syncthreads();
        f32x4 c00 = {0.f,0.f,0.f,0.f}, c01 = {0.f,0.f,0.f,0.f};
        f32x4 c10 = {0.f,0.f,0.f,0.f}, c11 = {0.f,0.f,0.f,0.f};
        #pragma unroll
        for (int kk = 0; kk < 64; kk += 32) {
            short8 a0 = *(const short8*)&As[wr + lr][kk + lk];
            short8 a1 = *(const short8*)&As[wr + 16 + lr][kk + lk];
            short8 b0 = *(const short8*)&Bs[wc + lr][kk + lk];
            short8 b1 = *(const short8*)&Bs[wc + 16 + lr][kk + lk];
            c00 = __builtin_amdgcn_mfma_f32_16x16x32_bf16(a0, b0, c00, 0, 0, 0);
            c01 = __builtin_amdgcn_mfma_f32_16x16x32_bf16(a0, b1, c01, 0, 0, 0);
            c10 = __builtin_amdgcn_mfma_f32_16x16x32_bf16(a1, b0, c10, 0, 0, 0);
            c11 = __builtin_amdgcn_mfma_f32_16x16x32_bf16(a1, b1, c11, 0, 0, 0);
        }
        f32x4 cc[2][2] = {{c00, c01}, {c10, c11}};
        #pragma unroll
        for (int i = 0; i < 2; i++)
            #pragma unroll
            for (int j = 0; j < 2; j++)
                #pragma unroll
                for (int rg = 0; rg < 4; rg++) {
                    int gr = rb + wr + i * 16 + drow + rg;
                    int gc = cb + wc + j * 16 + dcol;
                    if (gr >= N_NODES) continue;
                    float v = (cc[i][j][rg] + bcat[gc]) * qsc;
                    if (gc < 128) QS[gr * 256 + gc] = (_Float16)v;
                    else if (gc < 384) {
#if HAVE_FP8
                        unsigned pk = (unsigned)__builtin_amdgcn_cvt_pk_fp8_f32(v, v, 0, false);
                        KV[gr * 256 + gc - 128] = (unsigned char)(pk & 0xFF);
#else
                        KV[gr * 256 + gc - 128] = (_Float16)v;
#endif
                    }
                    else QS[gr * 256 + gc - 256] = (_Float16)v;
                }
    }
}

// ---------------- fused attention + skip + classifier ----------------
#if HAVE_FP8
static __device__ __forceinline__ void attn_edge(const f32x2* qf, uint2 ku, uint2 vu,
                                                 f32x2& o01, f32x2& o23, f32x2& o45, f32x2& o67,
                                                 float& d) {
    f32x2 k01 = __builtin_amdgcn_cvt_pk_f32_fp8(ku.x, false);
    f32x2 k23 = __builtin_amdgcn_cvt_pk_f32_fp8(ku.x, true);
    f32x2 k45 = __builtin_amdgcn_cvt_pk_f32_fp8(ku.y, false);
    f32x2 k67 = __builtin_amdgcn_cvt_pk_f32_fp8(ku.y, true);
    f32x2 s2 = qf[0] * k01 + qf[1] * k23 + qf[2] * k45 + qf[3] * k67;
    float s = s2.x + s2.y;
    s += __shfl_xor(s, 1);
    s += __shfl_xor(s, 2);
    float w = __builtin_amdgcn_exp2f(s);
    d += w;
    o01 += w * __builtin_amdgcn_cvt_pk_f32_fp8(vu.x, false);
    o23 += w * __builtin_amdgcn_cvt_pk_f32_fp8(vu.x, true);
    o45 += w * __builtin_amdgcn_cvt_pk_f32_fp8(vu.y, false);
    o67 += w * __builtin_amdgcn_cvt_pk_f32_fp8(vu.y, true);
}
#else
static __device__ __forceinline__ void attn_edge16(const f32x2* qf, uint4 ku, uint4 vu,
                                                   f32x2& o01, f32x2& o23, f32x2& o45, f32x2& o67,
                                                   float& d) {
    h2 k0 = __builtin_bit_cast(h2, ku.x), k1 = __builtin_bit_cast(h2, ku.y);
    h2 k2 = __builtin_bit_cast(h2, ku.z), k3 = __builtin_bit_cast(h2, ku.w);
    f32x2 s2 = qf[0] * f32x2{(float)k0.x, (float)k0.y} + qf[1] * f32x2{(float)k1.x, (float)k1.y}
             + qf[2] * f32x2{(float)k2.x, (float)k2.y} + qf[3] * f32x2{(float)k3.x, (float)k3.y};
    float s = s2.x + s2.y;
    s += __shfl_xor(s, 1);
    s += __shfl_xor(s, 2);
    float w = __builtin_amdgcn_exp2f(s);
    d += w;
    h2 v0 = __builtin_bit_cast(h2, vu.x), v1 = __builtin_bit_cast(h2, vu.y);
    h2 v2 = __builtin_bit_cast(h2, vu.z), v3 = __builtin_bit_cast(h2, vu.w);
    o01 += w * f32x2{(float)v0.x, (float)v0.y};
    o23 += w * f32x2{(float)v1.x, (float)v1.y};
    o45 += w * f32x2{(float)v2.x, (float)v2.y};
    o67 += w * f32x2{(float)v3.x, (float)v3.y};
}
#endif

__global__ __launch_bounds__(256) void attn_kernel(const _Float16* __restrict__ QS,
                                                   const void* __restrict__ KVp,
                                                   const uint4* __restrict__ bro,
                                                   const unsigned int* __restrict__ ep,
                                                   const float* __restrict__ Wf, const float* __restrict__ bfv,
                                                   float* __restrict__ out) {
    int t = threadIdx.x, lane = t & 63;
    int n = blockIdx.x * 4 + (t >> 6);
    if (n >= N_NODES) return;
    int slot = lane >> 4, pos = lane & 15;   // lane covers dims pos*8..pos*8+7; head = pos>>2
    const uint4* QS4 = (const uint4*)QS;
    uint4 qv = QS4[n * 32 + pos];
    h2 q0 = __builtin_bit_cast(h2, qv.x), q1 = __builtin_bit_cast(h2, qv.y);
    h2 q2 = __builtin_bit_cast(h2, qv.z), q3 = __builtin_bit_cast(h2, qv.w);
    f32x2 qf[4] = { f32x2{(float)q0.x, (float)q0.y}, f32x2{(float)q1.x, (float)q1.y},
                    f32x2{(float)q2.x, (float)q2.y}, f32x2{(float)q3.x, (float)q3.y} };
    f32x2 o01 = {0.f,0.f}, o23 = {0.f,0.f}, o45 = {0.f,0.f}, o67 = {0.f,0.f};
    float d = 0.f;
    uint4 bnd = bro[n];
    int p0 = (int)bnd.x, p1 = (int)bnd.w;
    int idx = p0 + slot;
#if HAVE_FP8
    const uint2* KV2 = (const uint2*)KVp;    // row = 256 B = 32 uint2; K at +pos, V at +16+pos
    while (idx + 12 < p1) {
        unsigned e0 = ep[idx], e1 = ep[idx + 4], e2 = ep[idx + 8], e3 = ep[idx + 12];
        int b0 = (int)(e0 >> 2) * 32 + pos;
        int b1 = (int)(e1 >> 2) * 32 + pos;
        int b2 = (int)(e2 >> 2) * 32 + pos;
        int b3 = (int)(e3 >> 2) * 32 + pos;
        uint2 k0 = KV2[b0], v0 = KV2[b0 + 16];
        uint2 k1 = KV2[b1], v1 = KV2[b1 + 16];
        uint2 k2 = KV2[b2], v2 = KV2[b2 + 16];
        uint2 k3 = KV2[b3], v3 = KV2[b3 + 16];
        attn_edge(qf, k0, v0, o01, o23, o45, o67, d);
        attn_edge(qf, k1, v1, o01, o23, o45, o67, d);
        attn_edge(qf, k2, v2, o01, o23, o45, o67, d);
        attn_edge(qf, k3, v3, o01, o23, o45, o67, d);
        idx += 16;
    }
    while (idx < p1) {
        unsigned e0 = ep[idx];
        int b0 = (int)(e0 >> 2) * 32 + pos;
        uint2 k0 = KV2[b0], v0 = KV2[b0 + 16];
        attn_edge(qf, k0, v0, o01, o23, o45, o67, d);
        idx += 4;
    }
#else
    const uint4* KV4 = (const uint4*)KVp;    // row = 512 B = 32 uint4; K at +pos, V at +16+pos
    while (idx + 12 < p1) {
        unsigned e0 = ep[idx], e1 = ep[idx + 4], e2 = ep[idx + 8], e3 = ep[idx + 12];
        int b0 = (int)(e0 >> 2) * 32 + pos;
        int b1 = (int)(e1 >> 2) * 32 + pos;
        int b2 = (int)(e2 >> 2) * 32 + pos;
        int b3 = (int)(e3 >> 2) * 32 + pos;
        uint4 k0 = KV4[b0], v0 = KV4[b0 + 16];
        uint4 k1 = KV4[b1], v1 = KV4[b1 + 16];
        uint4 k2 = KV4[b2], v2 = KV4[b2 + 16];
        uint4 k3 = KV4[b3], v3 = KV4[b3 + 16];
        attn_edge16(qf, k0, v0, o01, o23, o45, o67, d);
        attn_edge16(qf, k1, v1, o01, o23, o45, o67, d);
        attn_edge16(qf, k2, v2, o01, o23, o45, o67, d);
        attn_edge16(qf, k3, v3, o01, o23, o45, o67, d);
        idx += 16;
    }
    while (idx < p1) {
        unsigned e0 = ep[idx];
        int b0 = (int)(e0 >> 2) * 32 + pos;
        uint4 k0 = KV4[b0], v0 = KV4[b0 + 16];
        attn_edge16(qf, k0, v0, o01, o23, o45, o67, d);
        idx += 4;
    }
#endif
    // combine the 4 edge-slots
    float of[8] = { o01.x, o01.y, o23.x, o23.y, o45.x, o45.y, o67.x, o67.y };
    d += __shfl_xor(d, 16); d += __shfl_xor(d, 32);
    #pragma unroll
    for (int i = 0; i < 8; i++) { of[i] += __shfl_xor(of[i], 16); of[i] += __shfl_xor(of[i], 32); }
    float inv = (d > 0.f) ? 1.f / d : 0.f;
    uint4 sv = QS4[n * 32 + 16 + pos];
    h2 s0 = __builtin_bit_cast(h2, sv.x), s1 = __builtin_bit_cast(h2, sv.y);
    h2 s2 = __builtin_bit_cast(h2, sv.z), s3 = __builtin_bit_cast(h2, sv.w);
    float sf[8] = { (float)s0.x, (float)s0.y, (float)s1.x, (float)s1.y,
                    (float)s2.x, (float)s2.y, (float)s3.x, (float)s3.y };
    float rf[8];
    #pragma unroll
    for (int i = 0; i < 8; i++) rf[i] = fmaxf(sf[i] + of[i] * inv, 0.f);
    // classifier: slot s computes classes {s, s+4} over its 8 dims; reduce over 16 lanes
    int base_d = pos * 8;
    int cls1 = (slot < 3) ? slot + 4 : 0;   // slot 3's second class is discarded
    float a0 = 0.f, a1 = 0.f;
    #pragma unroll
    for (int i = 0; i < 8; i++) {
        a0 += rf[i] * Wf[(base_d + i) * 7 + slot];
        a1 += rf[i] * Wf[(base_d + i) * 7 + cls1];
    }
    a0 += __shfl_xor(a0, 1); a1 += __shfl_xor(a1, 1);
    a0 += __shfl_xor(a0, 2); a1 += __shfl_xor(a1, 2);
    a0 += __shfl_xor(a0, 4); a1 += __shfl_xor(a1, 4);
    a0 += __shfl_xor(a0, 8); a1 += __shfl_xor(a1, 8);
    if (pos == 0) {
        out[n * 7 + slot] = a0 + bfv[slot];
        if (slot < 3) out[n * 7 + slot + 4] = a1 + bfv[slot + 4];
    }
}

extern "C" void kernel_launch(void* const* d_in, const int* in_sizes, int n_in,
                              void* d_out, int out_size, void* d_ws, size_t ws_size,
                              hipStream_t stream) {
    const float* x     = (const float*)d_in[0];
    const int*   ei    = (const int*)d_in[2];
    const int*   et    = (const int*)d_in[3];
    const float* Wrel  = (const float*)d_in[4];
    const float* Wroot = (const float*)d_in[5];
    const float* brg   = (const float*)d_in[6];
    const float* Wq    = (const float*)d_in[7];
    const float* bq    = (const float*)d_in[8];
    const float* Wk    = (const float*)d_in[9];
    const float* bk    = (const float*)d_in[10];
    const float* Wv    = (const float*)d_in[11];
    const float* bv    = (const float*)d_in[12];
    const float* Wsk   = (const float*)d_in[13];
    const float* bsk   = (const float*)d_in[14];
    const float* Wf    = (const float*)d_in[15];
    const float* bfv   = (const float*)d_in[16];
    float* out = (float*)d_out;

    // workspace layout (~131 MB):
    //  [0,       51.2M)  hr_all bf16 [N][256] (dead after rgcn); QS fp16 [N][256] overlay
    //  [51.2M,  102.4M)  KV  (fp8 [N][256B] = 25.6M used, or fp16 [N][512B] = 51.2M)
    //  [102.4M, 115.2M)  Hm bf16 [N,64]
    //  [115.2M, 121.6M)  ep u32 [E]  (src<<2 | r)
    //  [121.6M, 128.0M)  rank u32 [E] (r<<28 | rank)
    //  [128.0M, 129.6M)  bro uint4 [N]
    //  then cntr (memset) / part / W1t / W2t / bcat
    char* ws = (char*)d_ws;
    unsigned short* hr_all = (unsigned short*)(ws + 0);
    _Float16*       QS     = (_Float16*)(ws + 0);
    void*           KV     = (void*)(ws + 51200000);
    unsigned short* Hm     = (unsigned short*)(ws + 102400000);
    unsigned int*   ep     = (unsigned int*)(ws + 115200000);
    unsigned*       rank   = (unsigned*)(ws + 121600000);
    uint4*          bro    = (uint4*)(ws + 128000000);
    int*            cntr   = (int*)(ws + 129600016);
    int*            part   = (int*)(ws + 130800016);
    unsigned short* W1t    = (unsigned short*)(ws + 130800528);
    unsigned short* W2t    = (unsigned short*)(ws + 130866064);
    float*          bcat   = (float*)(ws + 130931600);

    hipMemsetAsync(cntr, 0, 3 * N_NODES * sizeof(int), stream);

    repack_kernel<<<258, 256, 0, stream>>>(Wrel, Wroot, Wq, Wk, Wv, Wsk, bq, bk, bv, bsk, W1t, W2t, bcat);

    // CSR build by destination (rank+relation packed in hist; scatter has no atomics)
    hist_kernel<<<N_EDGES / 256, 256, 0, stream>>>(ei, et, cntr, rank);
    scanA_kernel<<<98, 256, 0, stream>>>(cntr, part);
    scanC_kernel<<<98, 256, 0, stream>>>(cntr, part, bro);
    scatter_kernel<<<N_EDGES / 256, 256, 0, stream>>>(ei, bro, rank, ep);

    // RGCN
    gemm1_mfma<<<1563, 256, 0, stream>>>(x, W1t, hr_all);
    rgcn_kernel<<<25000, 256, 0, stream>>>(hr_all, brg, bro, ep, Hm);

    // TransformerConv
    gemm2_mfma<<<1563, 256, 0, stream>>>(Hm, W2t, bcat, QS, KV);
    attn_kernel<<<25000, 256, 0, stream>>>(QS, KV, bro, ep, Wf, bfv, out);
}

// Round 10
// 563.052 us; speedup vs baseline: 1.0191x; 1.0191x over previous
//
#include <hip/hip_runtime.h>
#include <math.h>

#define N_NODES 100000
#define N_EDGES 1600000

typedef short short8 __attribute__((ext_vector_type(8)));
typedef float f32x4 __attribute__((ext_vector_type(4)));
typedef float f32x2 __attribute__((ext_vector_type(2)));
typedef _Float16 h2 __attribute__((ext_vector_type(2)));

// 1/sqrt(32) * log2(e)  (fold softmax scale + exp2 conversion into Q)
#define QSC 0.25503540f

#if defined(__has_builtin)
#if __has_builtin(__builtin_amdgcn_cvt_pk_f32_fp8) && __has_builtin(__builtin_amdgcn_cvt_pk_fp8_f32)
#define HAVE_FP8 1
#endif
#endif
#ifndef HAVE_FP8
#define HAVE_FP8 0
#endif

static __device__ __forceinline__ float bf2f(unsigned int u16) {
    return __uint_as_float(u16 << 16);
}
static __device__ __forceinline__ unsigned short f2bf(float f) {
    unsigned u = __float_as_uint(f);
    unsigned r = u + 0x7FFF + ((u >> 16) & 1);   // RTNE
    return (unsigned short)(r >> 16);
}
static __device__ __forceinline__ f32x2 bfpair(unsigned u) {
    f32x2 r;
    r.x = __uint_as_float(u << 16);
    r.y = __uint_as_float(u & 0xFFFF0000u);
    return r;
}

// ---------------- weight repack ----------------
__global__ void repack_kernel(const float* __restrict__ Wrel, const float* __restrict__ Wroot,
                              const float* __restrict__ Wq, const float* __restrict__ Wk,
                              const float* __restrict__ Wv, const float* __restrict__ Wsk,
                              const float* __restrict__ bq, const float* __restrict__ bk,
                              const float* __restrict__ bv, const float* __restrict__ bsk,
                              unsigned short* __restrict__ W1t, unsigned short* __restrict__ W2t,
                              float* __restrict__ bcat) {
    int idx = blockIdx.x * 256 + threadIdx.x;
    if (idx < 128 * 256) {
        int k = idx >> 8, c = idx & 255;
        float v;
        if (c < 192) { int r = c >> 6, cc = c & 63; v = Wrel[r * 8192 + k * 64 + cc]; }
        else v = Wroot[k * 64 + (c - 192)];
        W1t[c * 128 + k] = f2bf(v);
    }
    int i2 = idx - 128 * 256;
    if (i2 >= 0 && i2 < 64 * 512) {
        int k = i2 >> 9, c = i2 & 511;
        float v;
        if (c < 128) v = Wq[k * 128 + c];
        else if (c < 256) v = Wk[k * 128 + c - 128];
        else if (c < 384) v = Wv[k * 128 + c - 256];
        else v = Wsk[k * 128 + c - 384];
        W2t[c * 64 + k] = f2bf(v);
    }
    int i3 = idx - 128 * 256 - 64 * 512;
    if (i3 >= 0 && i3 < 512) {
        float v;
        if (i3 < 128) v = bq[i3];
        else if (i3 < 256) v = bk[i3 - 128];
        else if (i3 < 384) v = bv[i3 - 256];
        else v = bsk[i3 - 384];
        bcat[i3] = v;
    }
}

// ---------------- CSR build ----------------
// hist: per-(relation,dst) counts; rank packs [r:4 | rank:28]
__global__ void hist_kernel(const int* __restrict__ ei, const int* __restrict__ et,
                            int* __restrict__ cntr, unsigned* __restrict__ rank) {
    int e = blockIdx.x * 256 + threadIdx.x;
    if (e < N_EDGES) {
        int r = et[e];
        unsigned rk = (unsigned)atomicAdd(&cntr[r * N_NODES + ei[N_EDGES + e]], 1);
        rank[e] = rk | ((unsigned)r << 28);
    }
}

__global__ void scanA_kernel(const int* __restrict__ cntr, int* __restrict__ part) {
    __shared__ int wsum[4];
    int t = threadIdx.x;
    int base = blockIdx.x * 1024 + t * 4;
    int s = 0;
    for (int i = 0; i < 4; i++) {
        int idx = base + i;
        if (idx < N_NODES) s += cntr[idx] + cntr[N_NODES + idx] + cntr[2 * N_NODES + idx];
    }
    for (int off = 1; off < 64; off <<= 1) s += __shfl_xor(s, off);
    if ((t & 63) == 0) wsum[t >> 6] = s;
    __syncthreads();
    if (t == 0) part[blockIdx.x] = wsum[0] + wsum[1] + wsum[2] + wsum[3];
}

// scanC: bro[n] = {rs, rs+c0, rs+c0+c1, rs+c0+c1+c2}
__global__ void scanC_kernel(const int* __restrict__ cntr, const int* __restrict__ part,
                             uint4* __restrict__ bro) {
    __shared__ int wsum[4];
    __shared__ int ws2[4];
    int t = threadIdx.x;
    int lane = t & 63;
    int base = blockIdx.x * 1024 + t * 4;
    int c0v[4], c1v[4], c2v[4]; int tsum = 0;
    for (int i = 0; i < 4; i++) {
        int idx = base + i;
        if (idx < N_NODES) {
            c0v[i] = cntr[idx]; c1v[i] = cntr[N_NODES + idx]; c2v[i] = cntr[2 * N_NODES + idx];
        } else { c0v[i] = c1v[i] = c2v[i] = 0; }
        tsum += c0v[i] + c1v[i] + c2v[i];
    }
    int p = (t < blockIdx.x) ? part[t] : 0;
    for (int off = 1; off < 64; off <<= 1) p += __shfl_xor(p, off);
    if (lane == 0) ws2[t >> 6] = p;
    int x = tsum;
    for (int off = 1; off < 64; off <<= 1) { int y = __shfl_up(x, off); if (lane >= off) x += y; }
    if (lane == 63) wsum[t >> 6] = x;
    __syncthreads();
    if (t == 0) { int run = 0; for (int w = 0; w < 4; w++) { int tmp = wsum[w]; wsum[w] = run; run += tmp; } }
    __syncthreads();
    int bofs = ws2[0] + ws2[1] + ws2[2] + ws2[3];
    int excl = x - tsum + wsum[t >> 6] + bofs;
    for (int i = 0; i < 4; i++) {
        int idx = base + i;
        if (idx < N_NODES) {
            uint4 b;
            b.x = (unsigned)excl;
            b.y = (unsigned)(excl + c0v[i]);
            b.z = (unsigned)(excl + c0v[i] + c1v[i]);
            b.w = (unsigned)(excl + c0v[i] + c1v[i] + c2v[i]);
            bro[idx] = b;
        }
        excl += c0v[i] + c1v[i] + c2v[i];
    }
}

// scatter: no atomics — pos = bro[dst].sel(r) + rank
__global__ void scatter_kernel(const int* __restrict__ ei,
                               const uint4* __restrict__ bro, const unsigned* __restrict__ rank,
                               unsigned int* __restrict__ ep) {
    int e = blockIdx.x * 256 + threadIdx.x;
    if (e >= N_EDGES) return;
    int src = ei[e], dst = ei[N_EDGES + e];
    unsigned rkr = rank[e];
    int r = (int)(rkr >> 28);
    unsigned rk = rkr & 0x0FFFFFFFu;
    uint4 b = bro[dst];
    unsigned ofs = (r == 0) ? b.x : (r == 1) ? b.y : b.z;
    ep[ofs + rk] = ((unsigned)src << 2) | (unsigned)r;
}

// ---------------- GEMM1 (MFMA bf16): X[N,128] @ W1[128,256] -> hr_all bf16 [N][256] ----------------
__global__ __launch_bounds__(256) void gemm1_mfma(const float* __restrict__ X,
                                                  const unsigned short* __restrict__ W1t,
                                                  unsigned short* __restrict__ hr_all) {
    __shared__ unsigned short As[64][136];
    __shared__ unsigned short Bs[64][136];
    int t = threadIdx.x;
    int rb = blockIdx.x * 64;
    #pragma unroll
    for (int i = 0; i < 8; i++) {
        int lin = t + i * 256;
        int row = lin >> 5;
        int c4 = lin & 31;
        float4 v = make_float4(0.f, 0.f, 0.f, 0.f);
        int gr = rb + row;
        if (gr < N_NODES) v = *(const float4*)&X[gr * 128 + c4 * 4];
        unsigned w0 = (unsigned)f2bf(v.x) | ((unsigned)f2bf(v.y) << 16);
        unsigned w1 = (unsigned)f2bf(v.z) | ((unsigned)f2bf(v.w) << 16);
        *(uint2*)&As[row][c4 * 4] = make_uint2(w0, w1);
    }
    int w = t >> 6, l = t & 63;
    int wr = (w >> 1) * 32, wc = (w & 1) * 32;
    int lr = l & 15, lk = (l >> 4) * 8;
    int drow = (l >> 4) * 4;
    int dcol = l & 15;
    for (int cb4 = 0; cb4 < 4; cb4++) {
        int cb = cb4 * 64;
        __syncthreads();
        #pragma unroll
        for (int i = 0; i < 4; i++) {
            int lin = t + i * 256;
            int n = lin >> 4;
            int k8 = lin & 15;
            *(uint4*)&Bs[n][k8 * 8] = *(const uint4*)&W1t[(cb + n) * 128 + k8 * 8];
        }
        __syncthreads();
        f32x4 c00 = {0.f,0.f,0.f,0.f}, c01 = {0.f,0.f,0.f,0.f};
        f32x4 c10 = {0.f,0.f,0.f,0.f}, c11 = {0.f,0.f,0.f,0.f};
        #pragma unroll
        for (int kk = 0; kk < 128; kk += 32) {
            short8 a0 = *(const short8*)&As[wr + lr][kk + lk];
            short8 a1 = *(const short8*)&As[wr + 16 + lr][kk + lk];
            short8 b0 = *(const short8*)&Bs[wc + lr][kk + lk];
            short8 b1 = *(const short8*)&Bs[wc + 16 + lr][kk + lk];
            c00 = __builtin_amdgcn_mfma_f32_16x16x32_bf16(a0, b0, c00, 0, 0, 0);
            c01 = __builtin_amdgcn_mfma_f32_16x16x32_bf16(a0, b1, c01, 0, 0, 0);
            c10 = __builtin_amdgcn_mfma_f32_16x16x32_bf16(a1, b0, c10, 0, 0, 0);
            c11 = __builtin_amdgcn_mfma_f32_16x16x32_bf16(a1, b1, c11, 0, 0, 0);
        }
        f32x4 cc[2][2] = {{c00, c01}, {c10, c11}};
        #pragma unroll
        for (int i = 0; i < 2; i++)
            #pragma unroll
            for (int j = 0; j < 2; j++)
                #pragma unroll
                for (int rg = 0; rg < 4; rg++) {
                    int gr = rb + wr + i * 16 + drow + rg;
                    int gc = cb + wc + j * 16 + dcol;
                    if (gr < N_NODES) hr_all[gr * 256 + gc] = f2bf(cc[i][j][rg]);
                }
    }
}

// ---------------- RGCN aggregate: 4 edges/wave, chunked broadcast (one coalesced ep load / 64 edges) ----------------
__global__ __launch_bounds__(256) void rgcn_kernel(const unsigned short* __restrict__ hr,
                                                   const float* __restrict__ brg,
                                                   const uint4* __restrict__ bro,
                                                   const unsigned int* __restrict__ ep,
                                                   unsigned short* __restrict__ Hm) {
    int t = threadIdx.x, lane = t & 63;
    int n = blockIdx.x * 4 + (t >> 6);
    if (n >= N_NODES) return;
    int slot = lane >> 4, pos = lane & 15;
    const uint2* H2 = (const uint2*)hr;
    uint4 b = bro[n];
    int p0 = (int)b.x, p1 = (int)b.w;
    int c0 = (int)(b.y - b.x), c1 = (int)(b.z - b.y), c2 = (int)(b.w - b.z);
    float i0 = c0 ? 1.f / (float)c0 : 0.f;
    float i1 = c1 ? 1.f / (float)c1 : 0.f;
    float i2 = c2 ? 1.f / (float)c2 : 0.f;
    f32x2 a01 = {0.f, 0.f}, a23 = {0.f, 0.f};
    for (int base = p0; base < p1; base += 64) {
        int pc = base + lane;
        unsigned chunk = (pc < p1) ? ep[pc] : 0u;
        int cnt = min(64, p1 - base);
        int g0 = 0;
        for (; g0 + 16 <= cnt; g0 += 16) {       // fully valid: no masking
            int i0x = g0 + slot;
            int e0 = __shfl((int)chunk, i0x);
            int e1 = __shfl((int)chunk, i0x + 4);
            int e2 = __shfl((int)chunk, i0x + 8);
            int e3 = __shfl((int)chunk, i0x + 12);
            uint2 h0 = H2[(unsigned)e0 * 16 + pos];
            uint2 h1 = H2[(unsigned)e1 * 16 + pos];
            uint2 h2v = H2[(unsigned)e2 * 16 + pos];
            uint2 h3 = H2[(unsigned)e3 * 16 + pos];
            float w0 = ((e0 & 3) == 0) ? i0 : ((e0 & 3) == 1) ? i1 : i2;
            float w1 = ((e1 & 3) == 0) ? i0 : ((e1 & 3) == 1) ? i1 : i2;
            float w2 = ((e2 & 3) == 0) ? i0 : ((e2 & 3) == 1) ? i1 : i2;
            float w3 = ((e3 & 3) == 0) ? i0 : ((e3 & 3) == 1) ? i1 : i2;
            a01 += w0 * bfpair(h0.x); a23 += w0 * bfpair(h0.y);
            a01 += w1 * bfpair(h1.x); a23 += w1 * bfpair(h1.y);
            a01 += w2 * bfpair(h2v.x); a23 += w2 * bfpair(h2v.y);
            a01 += w3 * bfpair(h3.x); a23 += w3 * bfpair(h3.y);
        }
        for (; g0 < cnt; g0 += 8) {              // remainder: masked via weight
            int iA = g0 + slot, iB = iA + 4;
            int e0 = __shfl((int)chunk, iA);
            int e1 = __shfl((int)chunk, iB);
            uint2 h0 = H2[(unsigned)e0 * 16 + pos];
            uint2 h1 = H2[(unsigned)e1 * 16 + pos];
            float w0 = ((e0 & 3) == 0) ? i0 : ((e0 & 3) == 1) ? i1 : i2;
            float w1 = ((e1 & 3) == 0) ? i0 : ((e1 & 3) == 1) ? i1 : i2;
            w0 = (iA < cnt) ? w0 : 0.f;
            w1 = (iB < cnt) ? w1 : 0.f;
            a01 += w0 * bfpair(h0.x); a23 += w0 * bfpair(h0.y);
            a01 += w1 * bfpair(h1.x); a23 += w1 * bfpair(h1.y);
        }
    }
    a01.x += __shfl_xor(a01.x, 16); a01.x += __shfl_xor(a01.x, 32);
    a01.y += __shfl_xor(a01.y, 16); a01.y += __shfl_xor(a01.y, 32);
    a23.x += __shfl_xor(a23.x, 16); a23.x += __shfl_xor(a23.x, 32);
    a23.y += __shfl_xor(a23.y, 16); a23.y += __shfl_xor(a23.y, 32);
    uint2 rt = H2[(n * 4 + 3) * 16 + pos];   // root block
    f32x2 r01 = bfpair(rt.x), r23 = bfpair(rt.y);
    float4 bb = ((const float4*)brg)[pos];
    float h0 = fmaxf(r01.x + bb.x + a01.x, 0.f);
    float h1 = fmaxf(r01.y + bb.y + a01.y, 0.f);
    float h2s = fmaxf(r23.x + bb.z + a23.x, 0.f);
    float h3 = fmaxf(r23.y + bb.w + a23.y, 0.f);
    if (slot == 0) {
        uint2 wv;
        wv.x = (unsigned)f2bf(h0) | ((unsigned)f2bf(h1) << 16);
        wv.y = (unsigned)f2bf(h2s) | ((unsigned)f2bf(h3) << 16);
        ((uint2*)Hm)[n * 16 + pos] = wv;
    }
}

// ---------------- GEMM2 (MFMA bf16): Hm[N,64] @ W2[64,512] + bcat ----------------
// QS fp16 row: [Q(128, pre-scaled by QSC) | skip(128)]
// KV: fp8 row [K|V] (256 B) if HAVE_FP8, else fp16 row [K|V] (512 B)
__global__ __launch_bounds__(256) void gemm2_mfma(const unsigned short* __restrict__ Hm,
                                                  const unsigned short* __restrict__ W2t,
                                                  const float* __restrict__ bcat,
                                                  _Float16* __restrict__ QS, void* __restrict__ KVp) {
#if HAVE_FP8
    unsigned char* KV = (unsigned char*)KVp;
#else
    _Float16* KV = (_Float16*)KVp;
#endif
    __shared__ unsigned short As[64][72];
    __shared__ unsigned short Bs[64][72];
    int t = threadIdx.x;
    int rb = blockIdx.x * 64;
    #pragma unroll
    for (int i = 0; i < 2; i++) {
        int lin = t + i * 256;
        int row = lin >> 3;
        int k8 = lin & 7;
        uint4 v = make_uint4(0, 0, 0, 0);
        int gr = rb + row;
        if (gr < N_NODES) v = *(const uint4*)&Hm[gr * 64 + k8 * 8];
        *(uint4*)&As[row][k8 * 8] = v;
    }
    int w = t >> 6, l = t & 63;
    int wr = (w >> 1) * 32, wc = (w & 1) * 32;
    int lr = l & 15, lk = (l >> 4) * 8;
    int drow = (l >> 4) * 4;
    int dcol = l & 15;
    for (int cb8 = 0; cb8 < 8; cb8++) {
        int cb = cb8 * 64;
        float qsc = (cb8 < 2) ? QSC : 1.f;
        __syncthreads();
        #pragma unroll
        for (int i = 0; i < 2; i++) {
            int lin = t + i * 256;
            int n = lin >> 3;
            int k8 = lin & 7;
            *(uint4*)&Bs[n][k8 * 8] = *(const uint4*)&W2t[(cb + n) * 64 + k8 * 8];
        }
        __syncthreads();
        f32x4 c00 = {0.f,0.f,0.f,0.f}, c01 = {0.f,0.f,0.f,0.f};
        f32x4 c10 = {0.f,0.f,0.f,0.f}, c11 = {0.f,0.f,0.f,0.f};
        #pragma unroll
        for (int kk = 0; kk < 64; kk += 32) {
            short8 a0 = *(const short8*)&As[wr + lr][kk + lk];
            short8 a1 = *(const short8*)&As[wr + 16 + lr][kk + lk];
            short8 b0 = *(const short8*)&Bs[wc + lr][kk + lk];
            short8 b1 = *(const short8*)&Bs[wc + 16 + lr][kk + lk];
            c00 = __builtin_amdgcn_mfma_f32_16x16x32_bf16(a0, b0, c00, 0, 0, 0);
            c01 = __builtin_amdgcn_mfma_f32_16x16x32_bf16(a0, b1, c01, 0, 0, 0);
            c10 = __builtin_amdgcn_mfma_f32_16x16x32_bf16(a1, b0, c10, 0, 0, 0);
            c11 = __builtin_amdgcn_mfma_f32_16x16x32_bf16(a1, b1, c11, 0, 0, 0);
        }
        f32x4 cc[2][2] = {{c00, c01}, {c10, c11}};
        #pragma unroll
        for (int i = 0; i < 2; i++)
            #pragma unroll
            for (int j = 0; j < 2; j++)
                #pragma unroll
                for (int rg = 0; rg < 4; rg++) {
                    int gr = rb + wr + i * 16 + drow + rg;
                    int gc = cb + wc + j * 16 + dcol;
                    if (gr >= N_NODES) continue;
                    float v = (cc[i][j][rg] + bcat[gc]) * qsc;
                    if (gc < 128) QS[gr * 256 + gc] = (_Float16)v;
                    else if (gc < 384) {
#if HAVE_FP8
                        unsigned pk = (unsigned)__builtin_amdgcn_cvt_pk_fp8_f32(v, v, 0, false);
                        KV[gr * 256 + gc - 128] = (unsigned char)(pk & 0xFF);
#else
                        KV[gr * 256 + gc - 128] = (_Float16)v;
#endif
                    }
                    else QS[gr * 256 + gc - 256] = (_Float16)v;
                }
    }
}

// ---------------- fused attention + skip + classifier: chunked broadcast + fp8 KV ----------------
#if HAVE_FP8
static __device__ __forceinline__ float attn_dot(const f32x2* qf, uint2 ku) {
    f32x2 k01 = __builtin_amdgcn_cvt_pk_f32_fp8(ku.x, false);
    f32x2 k23 = __builtin_amdgcn_cvt_pk_f32_fp8(ku.x, true);
    f32x2 k45 = __builtin_amdgcn_cvt_pk_f32_fp8(ku.y, false);
    f32x2 k67 = __builtin_amdgcn_cvt_pk_f32_fp8(ku.y, true);
    f32x2 s2 = qf[0] * k01 + qf[1] * k23 + qf[2] * k45 + qf[3] * k67;
    float s = s2.x + s2.y;
    s += __shfl_xor(s, 1);
    s += __shfl_xor(s, 2);
    return s;
}
static __device__ __forceinline__ void attn_pv(float w, uint2 vu,
                                               f32x2& o01, f32x2& o23, f32x2& o45, f32x2& o67) {
    o01 += w * __builtin_amdgcn_cvt_pk_f32_fp8(vu.x, false);
    o23 += w * __builtin_amdgcn_cvt_pk_f32_fp8(vu.x, true);
    o45 += w * __builtin_amdgcn_cvt_pk_f32_fp8(vu.y, false);
    o67 += w * __builtin_amdgcn_cvt_pk_f32_fp8(vu.y, true);
}
#else
static __device__ __forceinline__ float attn_dot16(const f32x2* qf, uint4 ku) {
    h2 k0 = __builtin_bit_cast(h2, ku.x), k1 = __builtin_bit_cast(h2, ku.y);
    h2 k2 = __builtin_bit_cast(h2, ku.z), k3 = __builtin_bit_cast(h2, ku.w);
    f32x2 s2 = qf[0] * f32x2{(float)k0.x, (float)k0.y} + qf[1] * f32x2{(float)k1.x, (float)k1.y}
             + qf[2] * f32x2{(float)k2.x, (float)k2.y} + qf[3] * f32x2{(float)k3.x, (float)k3.y};
    float s = s2.x + s2.y;
    s += __shfl_xor(s, 1);
    s += __shfl_xor(s, 2);
    return s;
}
static __device__ __forceinline__ void attn_pv16(float w, uint4 vu,
                                                 f32x2& o01, f32x2& o23, f32x2& o45, f32x2& o67) {
    h2 v0 = __builtin_bit_cast(h2, vu.x), v1 = __builtin_bit_cast(h2, vu.y);
    h2 v2 = __builtin_bit_cast(h2, vu.z), v3 = __builtin_bit_cast(h2, vu.w);
    o01 += w * f32x2{(float)v0.x, (float)v0.y};
    o23 += w * f32x2{(float)v1.x, (float)v1.y};
    o45 += w * f32x2{(float)v2.x, (float)v2.y};
    o67 += w * f32x2{(float)v3.x, (float)v3.y};
}
#endif

__global__ __launch_bounds__(256) void attn_kernel(const _Float16* __restrict__ QS,
                                                   const void* __restrict__ KVp,
                                                   const uint4* __restrict__ bro,
                                                   const unsigned int* __restrict__ ep,
                                                   const float* __restrict__ Wf, const float* __restrict__ bfv,
                                                   float* __restrict__ out) {
    int t = threadIdx.x, lane = t & 63;
    int n = blockIdx.x * 4 + (t >> 6);
    if (n >= N_NODES) return;
    int slot = lane >> 4, pos = lane & 15;   // lane covers dims pos*8..pos*8+7 of edge-slot `slot`
    const uint4* QS4 = (const uint4*)QS;
    uint4 qv = QS4[n * 32 + pos];
    h2 q0 = __builtin_bit_cast(h2, qv.x), q1 = __builtin_bit_cast(h2, qv.y);
    h2 q2 = __builtin_bit_cast(h2, qv.z), q3 = __builtin_bit_cast(h2, qv.w);
    f32x2 qf[4] = { f32x2{(float)q0.x, (float)q0.y}, f32x2{(float)q1.x, (float)q1.y},
                    f32x2{(float)q2.x, (float)q2.y}, f32x2{(float)q3.x, (float)q3.y} };
    f32x2 o01 = {0.f,0.f}, o23 = {0.f,0.f}, o45 = {0.f,0.f}, o67 = {0.f,0.f};
    float d = 0.f;
    uint4 bnd = bro[n];
    int p0 = (int)bnd.x, p1 = (int)bnd.w;
    for (int base = p0; base < p1; base += 64) {
        int pc = base + lane;
        unsigned chunk = (pc < p1) ? ep[pc] : 0u;
        int cnt = min(64, p1 - base);
        int g0 = 0;
#if HAVE_FP8
        const uint2* KV2 = (const uint2*)KVp;    // row = 256 B = 32 uint2; K at +pos, V at +16+pos
        for (; g0 + 16 <= cnt; g0 += 16) {       // fully valid: no masking
            int i0 = g0 + slot;
            int e0 = __shfl((int)chunk, i0);
            int e1 = __shfl((int)chunk, i0 + 4);
            int e2 = __shfl((int)chunk, i0 + 8);
            int e3 = __shfl((int)chunk, i0 + 12);
            int b0 = (int)((unsigned)e0 >> 2) * 32 + pos;
            int b1 = (int)((unsigned)e1 >> 2) * 32 + pos;
            int b2 = (int)((unsigned)e2 >> 2) * 32 + pos;
            int b3 = (int)((unsigned)e3 >> 2) * 32 + pos;
            uint2 k0 = KV2[b0], v0 = KV2[b0 + 16];
            uint2 k1 = KV2[b1], v1 = KV2[b1 + 16];
            uint2 k2 = KV2[b2], v2 = KV2[b2 + 16];
            uint2 k3 = KV2[b3], v3 = KV2[b3 + 16];
            float s0 = attn_dot(qf, k0), s1 = attn_dot(qf, k1);
            float s2 = attn_dot(qf, k2), s3 = attn_dot(qf, k3);
            float w0 = __builtin_amdgcn_exp2f(s0);
            float w1 = __builtin_amdgcn_exp2f(s1);
            float w2 = __builtin_amdgcn_exp2f(s2);
            float w3 = __builtin_amdgcn_exp2f(s3);
            d += (w0 + w1) + (w2 + w3);
            attn_pv(w0, v0, o01, o23, o45, o67);
            attn_pv(w1, v1, o01, o23, o45, o67);
            attn_pv(w2, v2, o01, o23, o45, o67);
            attn_pv(w3, v3, o01, o23, o45, o67);
        }
        for (; g0 < cnt; g0 += 8) {              // remainder: masked
            int iA = g0 + slot, iB = iA + 4;
            int e0 = __shfl((int)chunk, iA);
            int e1 = __shfl((int)chunk, iB);
            int b0 = (int)((unsigned)e0 >> 2) * 32 + pos;
            int b1 = (int)((unsigned)e1 >> 2) * 32 + pos;
            uint2 k0 = KV2[b0], v0 = KV2[b0 + 16];
            uint2 k1 = KV2[b1], v1 = KV2[b1 + 16];
            float s0 = attn_dot(qf, k0), s1 = attn_dot(qf, k1);
            float w0 = (iA < cnt) ? __builtin_amdgcn_exp2f(s0) : 0.f;
            float w1 = (iB < cnt) ? __builtin_amdgcn_exp2f(s1) : 0.f;
            d += w0 + w1;
            attn_pv(w0, v0, o01, o23, o45, o67);
            attn_pv(w1, v1, o01, o23, o45, o67);
        }
#else
        const uint4* KV4 = (const uint4*)KVp;    // row = 512 B = 32 uint4
        for (; g0 + 16 <= cnt; g0 += 16) {
            int i0 = g0 + slot;
            int e0 = __shfl((int)chunk, i0);
            int e1 = __shfl((int)chunk, i0 + 4);
            int e2 = __shfl((int)chunk, i0 + 8);
            int e3 = __shfl((int)chunk, i0 + 12);
            int b0 = (int)((unsigned)e0 >> 2) * 32 + pos;
            int b1 = (int)((unsigned)e1 >> 2) * 32 + pos;
            int b2 = (int)((unsigned)e2 >> 2) * 32 + pos;
            int b3 = (int)((unsigned)e3 >> 2) * 32 + pos;
            uint4 k0 = KV4[b0], v0 = KV4[b0 + 16];
            uint4 k1 = KV4[b1], v1 = KV4[b1 + 16];
            uint4 k2 = KV4[b2], v2 = KV4[b2 + 16];
            uint4 k3 = KV4[b3], v3 = KV4[b3 + 16];
            float s0 = attn_dot16(qf, k0), s1 = attn_dot16(qf, k1);
            float s2 = attn_dot16(qf, k2), s3 = attn_dot16(qf, k3);
            float w0 = __builtin_amdgcn_exp2f(s0);
            float w1 = __builtin_amdgcn_exp2f(s1);
            float w2 = __builtin_amdgcn_exp2f(s2);
            float w3 = __builtin_amdgcn_exp2f(s3);
            d += (w0 + w1) + (w2 + w3);
            attn_pv16(w0, v0, o01, o23, o45, o67);
            attn_pv16(w1, v1, o01, o23, o45, o67);
            attn_pv16(w2, v2, o01, o23, o45, o67);
            attn_pv16(w3, v3, o01, o23, o45, o67);
        }
        for (; g0 < cnt; g0 += 8) {
            int iA = g0 + slot, iB = iA + 4;
            int e0 = __shfl((int)chunk, iA);
            int e1 = __shfl((int)chunk, iB);
            int b0 = (int)((unsigned)e0 >> 2) * 32 + pos;
            int b1 = (int)((unsigned)e1 >> 2) * 32 + pos;
            uint4 k0 = KV4[b0], v0 = KV4[b0 + 16];
            uint4 k1 = KV4[b1], v1 = KV4[b1 + 16];
            float s0 = attn_dot16(qf, k0), s1 = attn_dot16(qf, k1);
            float w0 = (iA < cnt) ? __builtin_amdgcn_exp2f(s0) : 0.f;
            float w1 = (iB < cnt) ? __builtin_amdgcn_exp2f(s1) : 0.f;
            d += w0 + w1;
            attn_pv16(w0, v0, o01, o23, o45, o67);
            attn_pv16(w1, v1, o01, o23, o45, o67);
        }
#endif
    }
    // combine the 4 edge-slots
    float of[8] = { o01.x, o01.y, o23.x, o23.y, o45.x, o45.y, o67.x, o67.y };
    d += __shfl_xor(d, 16); d += __shfl_xor(d, 32);
    #pragma unroll
    for (int i = 0; i < 8; i++) { of[i] += __shfl_xor(of[i], 16); of[i] += __shfl_xor(of[i], 32); }
    float inv = (d > 0.f) ? 1.f / d : 0.f;
    uint4 sv = QS4[n * 32 + 16 + pos];
    h2 s0h = __builtin_bit_cast(h2, sv.x), s1h = __builtin_bit_cast(h2, sv.y);
    h2 s2h = __builtin_bit_cast(h2, sv.z), s3h = __builtin_bit_cast(h2, sv.w);
    float sf[8] = { (float)s0h.x, (float)s0h.y, (float)s1h.x, (float)s1h.y,
                    (float)s2h.x, (float)s2h.y, (float)s3h.x, (float)s3h.y };
    float rf[8];
    #pragma unroll
    for (int i = 0; i < 8; i++) rf[i] = fmaxf(sf[i] + of[i] * inv, 0.f);
    // classifier: slot s computes classes {s, s+4} over its 8 dims; reduce over 16 lanes
    int base_d = pos * 8;
    int cls1 = (slot < 3) ? slot + 4 : 0;   // slot 3's second class is discarded
    float a0 = 0.f, a1 = 0.f;
    #pragma unroll
    for (int i = 0; i < 8; i++) {
        a0 += rf[i] * Wf[(base_d + i) * 7 + slot];
        a1 += rf[i] * Wf[(base_d + i) * 7 + cls1];
    }
    a0 += __shfl_xor(a0, 1); a1 += __shfl_xor(a1, 1);
    a0 += __shfl_xor(a0, 2); a1 += __shfl_xor(a1, 2);
    a0 += __shfl_xor(a0, 4); a1 += __shfl_xor(a1, 4);
    a0 += __shfl_xor(a0, 8); a1 += __shfl_xor(a1, 8);
    if (pos == 0) {
        out[n * 7 + slot] = a0 + bfv[slot];
        if (slot < 3) out[n * 7 + slot + 4] = a1 + bfv[slot + 4];
    }
}

extern "C" void kernel_launch(void* const* d_in, const int* in_sizes, int n_in,
                              void* d_out, int out_size, void* d_ws, size_t ws_size,
                              hipStream_t stream) {
    const float* x     = (const float*)d_in[0];
    const int*   ei    = (const int*)d_in[2];
    const int*   et    = (const int*)d_in[3];
    const float* Wrel  = (const float*)d_in[4];
    const float* Wroot = (const float*)d_in[5];
    const float* brg   = (const float*)d_in[6];
    const float* Wq    = (const float*)d_in[7];
    const float* bq    = (const float*)d_in[8];
    const float* Wk    = (const float*)d_in[9];
    const float* bk    = (const float*)d_in[10];
    const float* Wv    = (const float*)d_in[11];
    const float* bv    = (const float*)d_in[12];
    const float* Wsk   = (const float*)d_in[13];
    const float* bsk   = (const float*)d_in[14];
    const float* Wf    = (const float*)d_in[15];
    const float* bfv   = (const float*)d_in[16];
    float* out = (float*)d_out;

    // workspace layout (~131 MB):
    //  [0,       51.2M)  hr_all bf16 [N][256] (dead after rgcn); QS fp16 [N][256] overlay
    //  [51.2M,  102.4M)  KV  (fp8 [N][256B] = 25.6M used, or fp16 [N][512B] = 51.2M)
    //  [102.4M, 115.2M)  Hm bf16 [N,64]
    //  [115.2M, 121.6M)  ep u32 [E]  (src<<2 | r)
    //  [121.6M, 128.0M)  rank u32 [E] (r<<28 | rank)
    //  [128.0M, 129.6M)  bro uint4 [N]
    //  then cntr (memset) / part / W1t / W2t / bcat
    char* ws = (char*)d_ws;
    unsigned short* hr_all = (unsigned short*)(ws + 0);
    _Float16*       QS     = (_Float16*)(ws + 0);
    void*           KV     = (void*)(ws + 51200000);
    unsigned short* Hm     = (unsigned short*)(ws + 102400000);
    unsigned int*   ep     = (unsigned int*)(ws + 115200000);
    unsigned*       rank   = (unsigned*)(ws + 121600000);
    uint4*          bro    = (uint4*)(ws + 128000000);
    int*            cntr   = (int*)(ws + 129600016);
    int*            part   = (int*)(ws + 130800016);
    unsigned short* W1t    = (unsigned short*)(ws + 130800528);
    unsigned short* W2t    = (unsigned short*)(ws + 130866064);
    float*          bcat   = (float*)(ws + 130931600);

    hipMemsetAsync(cntr, 0, 3 * N_NODES * sizeof(int), stream);

    repack_kernel<<<258, 256, 0, stream>>>(Wrel, Wroot, Wq, Wk, Wv, Wsk, bq, bk, bv, bsk, W1t, W2t, bcat);

    // CSR build by destination (rank+relation packed in hist; scatter has no atomics)
    hist_kernel<<<N_EDGES / 256, 256, 0, stream>>>(ei, et, cntr, rank);
    scanA_kernel<<<98, 256, 0, stream>>>(cntr, part);
    scanC_kernel<<<98, 256, 0, stream>>>(cntr, part, bro);
    scatter_kernel<<<N_EDGES / 256, 256, 0, stream>>>(ei, bro, rank, ep);

    // RGCN
    gemm1_mfma<<<1563, 256, 0, stream>>>(x, W1t, hr_all);
    rgcn_kernel<<<25000, 256, 0, stream>>>(hr_all, brg, bro, ep, Hm);

    // TransformerConv
    gemm2_mfma<<<1563, 256, 0, stream>>>(Hm, W2t, bcat, QS, KV);
    attn_kernel<<<25000, 256, 0, stream>>>(QS, KV, bro, ep, Wf, bfv, out);
}

// Round 11
// 548.088 us; speedup vs baseline: 1.0469x; 1.0273x over previous
//
#include <hip/hip_runtime.h>
#include <math.h>

#define N_NODES 100000
#define N_EDGES 1600000

typedef short short8 __attribute__((ext_vector_type(8)));
typedef float f32x4 __attribute__((ext_vector_type(4)));
typedef float f32x2 __attribute__((ext_vector_type(2)));
typedef _Float16 h2 __attribute__((ext_vector_type(2)));

// 1/sqrt(32) * log2(e)  (fold softmax scale + exp2 conversion into Q)
#define QSC 0.25503540f

static __device__ __forceinline__ float bf2f(unsigned int u16) {
    return __uint_as_float(u16 << 16);
}
static __device__ __forceinline__ unsigned short f2bf(float f) {
    unsigned u = __float_as_uint(f);
    unsigned r = u + 0x7FFF + ((u >> 16) & 1);   // RTNE
    return (unsigned short)(r >> 16);
}
static __device__ __forceinline__ f32x2 bfpair(unsigned u) {
    f32x2 r;
    r.x = __uint_as_float(u << 16);
    r.y = __uint_as_float(u & 0xFFFF0000u);
    return r;
}
static __device__ __forceinline__ float dot8h(const h2* q, uint4 k) {
    h2 s = q[0] * __builtin_bit_cast(h2, k.x);
    s += q[1] * __builtin_bit_cast(h2, k.y);
    s += q[2] * __builtin_bit_cast(h2, k.z);
    s += q[3] * __builtin_bit_cast(h2, k.w);
    return (float)s.x + (float)s.y;
}
static __device__ __forceinline__ void pv8h(h2* o, float w, uint4 v) {
    _Float16 wh = (_Float16)w;
    o[0] += wh * __builtin_bit_cast(h2, v.x);
    o[1] += wh * __builtin_bit_cast(h2, v.y);
    o[2] += wh * __builtin_bit_cast(h2, v.z);
    o[3] += wh * __builtin_bit_cast(h2, v.w);
}

// ---------------- weight repack ----------------
__global__ void repack_kernel(const float* __restrict__ Wrel, const float* __restrict__ Wroot,
                              const float* __restrict__ Wq, const float* __restrict__ Wk,
                              const float* __restrict__ Wv, const float* __restrict__ Wsk,
                              const float* __restrict__ bq, const float* __restrict__ bk,
                              const float* __restrict__ bv, const float* __restrict__ bsk,
                              unsigned short* __restrict__ W1t, unsigned short* __restrict__ W2t,
                              float* __restrict__ bcat) {
    int idx = blockIdx.x * 256 + threadIdx.x;
    if (idx < 128 * 256) {
        int k = idx >> 8, c = idx & 255;
        float v;
        if (c < 192) { int r = c >> 6, cc = c & 63; v = Wrel[r * 8192 + k * 64 + cc]; }
        else v = Wroot[k * 64 + (c - 192)];
        W1t[c * 128 + k] = f2bf(v);
    }
    int i2 = idx - 128 * 256;
    if (i2 >= 0 && i2 < 64 * 512) {
        int k = i2 >> 9, c = i2 & 511;
        float v;
        if (c < 128) v = Wq[k * 128 + c];
        else if (c < 256) v = Wk[k * 128 + c - 128];
        else if (c < 384) v = Wv[k * 128 + c - 256];
        else v = Wsk[k * 128 + c - 384];
        W2t[c * 64 + k] = f2bf(v);
    }
    int i3 = idx - 128 * 256 - 64 * 512;
    if (i3 >= 0 && i3 < 512) {
        float v;
        if (i3 < 128) v = bq[i3];
        else if (i3 < 256) v = bk[i3 - 128];
        else if (i3 < 384) v = bv[i3 - 256];
        else v = bsk[i3 - 384];
        bcat[i3] = v;
    }
}

// ---------------- CSR build ----------------
// hist: per-(relation,dst) counts; rank packs [r:4 | rank:28]
__global__ void hist_kernel(const int* __restrict__ ei, const int* __restrict__ et,
                            int* __restrict__ cntr, unsigned* __restrict__ rank) {
    int e = blockIdx.x * 256 + threadIdx.x;
    if (e < N_EDGES) {
        int r = et[e];
        unsigned rk = (unsigned)atomicAdd(&cntr[r * N_NODES + ei[N_EDGES + e]], 1);
        rank[e] = rk | ((unsigned)r << 28);
    }
}

__global__ void scanA_kernel(const int* __restrict__ cntr, int* __restrict__ part) {
    __shared__ int wsum[4];
    int t = threadIdx.x;
    int base = blockIdx.x * 1024 + t * 4;
    int s = 0;
    for (int i = 0; i < 4; i++) {
        int idx = base + i;
        if (idx < N_NODES) s += cntr[idx] + cntr[N_NODES + idx] + cntr[2 * N_NODES + idx];
    }
    for (int off = 1; off < 64; off <<= 1) s += __shfl_xor(s, off);
    if ((t & 63) == 0) wsum[t >> 6] = s;
    __syncthreads();
    if (t == 0) part[blockIdx.x] = wsum[0] + wsum[1] + wsum[2] + wsum[3];
}

// scanC: bro[n] = {rs, rs+c0, rs+c0+c1, rs+c0+c1+c2}
__global__ void scanC_kernel(const int* __restrict__ cntr, const int* __restrict__ part,
                             uint4* __restrict__ bro) {
    __shared__ int wsum[4];
    __shared__ int ws2[4];
    int t = threadIdx.x;
    int lane = t & 63;
    int base = blockIdx.x * 1024 + t * 4;
    int c0v[4], c1v[4], c2v[4]; int tsum = 0;
    for (int i = 0; i < 4; i++) {
        int idx = base + i;
        if (idx < N_NODES) {
            c0v[i] = cntr[idx]; c1v[i] = cntr[N_NODES + idx]; c2v[i] = cntr[2 * N_NODES + idx];
        } else { c0v[i] = c1v[i] = c2v[i] = 0; }
        tsum += c0v[i] + c1v[i] + c2v[i];
    }
    int p = (t < blockIdx.x) ? part[t] : 0;
    for (int off = 1; off < 64; off <<= 1) p += __shfl_xor(p, off);
    if (lane == 0) ws2[t >> 6] = p;
    int x = tsum;
    for (int off = 1; off < 64; off <<= 1) { int y = __shfl_up(x, off); if (lane >= off) x += y; }
    if (lane == 63) wsum[t >> 6] = x;
    __syncthreads();
    if (t == 0) { int run = 0; for (int w = 0; w < 4; w++) { int tmp = wsum[w]; wsum[w] = run; run += tmp; } }
    __syncthreads();
    int bofs = ws2[0] + ws2[1] + ws2[2] + ws2[3];
    int excl = x - tsum + wsum[t >> 6] + bofs;
    for (int i = 0; i < 4; i++) {
        int idx = base + i;
        if (idx < N_NODES) {
            uint4 b;
            b.x = (unsigned)excl;
            b.y = (unsigned)(excl + c0v[i]);
            b.z = (unsigned)(excl + c0v[i] + c1v[i]);
            b.w = (unsigned)(excl + c0v[i] + c1v[i] + c2v[i]);
            bro[idx] = b;
        }
        excl += c0v[i] + c1v[i] + c2v[i];
    }
}

// scatter: no atomics — pos = bro[dst].sel(r) + rank
__global__ void scatter_kernel(const int* __restrict__ ei,
                               const uint4* __restrict__ bro, const unsigned* __restrict__ rank,
                               unsigned int* __restrict__ ep) {
    int e = blockIdx.x * 256 + threadIdx.x;
    if (e >= N_EDGES) return;
    int src = ei[e], dst = ei[N_EDGES + e];
    unsigned rkr = rank[e];
    int r = (int)(rkr >> 28);
    unsigned rk = rkr & 0x0FFFFFFFu;
    uint4 b = bro[dst];
    unsigned ofs = (r == 0) ? b.x : (r == 1) ? b.y : b.z;
    ep[ofs + rk] = ((unsigned)src << 2) | (unsigned)r;
}

// ---------------- GEMM1 (MFMA bf16): X[N,128] @ W1[128,256] -> hr_all bf16 [N][256] ----------------
__global__ __launch_bounds__(256) void gemm1_mfma(const float* __restrict__ X,
                                                  const unsigned short* __restrict__ W1t,
                                                  unsigned short* __restrict__ hr_all) {
    __shared__ unsigned short As[64][136];
    __shared__ unsigned short Bs[64][136];
    int t = threadIdx.x;
    int rb = blockIdx.x * 64;
    #pragma unroll
    for (int i = 0; i < 8; i++) {
        int lin = t + i * 256;
        int row = lin >> 5;
        int c4 = lin & 31;
        float4 v = make_float4(0.f, 0.f, 0.f, 0.f);
        int gr = rb + row;
        if (gr < N_NODES) v = *(const float4*)&X[gr * 128 + c4 * 4];
        unsigned w0 = (unsigned)f2bf(v.x) | ((unsigned)f2bf(v.y) << 16);
        unsigned w1 = (unsigned)f2bf(v.z) | ((unsigned)f2bf(v.w) << 16);
        *(uint2*)&As[row][c4 * 4] = make_uint2(w0, w1);
    }
    int w = t >> 6, l = t & 63;
    int wr = (w >> 1) * 32, wc = (w & 1) * 32;
    int lr = l & 15, lk = (l >> 4) * 8;
    int drow = (l >> 4) * 4;
    int dcol = l & 15;
    for (int cb4 = 0; cb4 < 4; cb4++) {
        int cb = cb4 * 64;
        __syncthreads();
        #pragma unroll
        for (int i = 0; i < 4; i++) {
            int lin = t + i * 256;
            int n = lin >> 4;
            int k8 = lin & 15;
            *(uint4*)&Bs[n][k8 * 8] = *(const uint4*)&W1t[(cb + n) * 128 + k8 * 8];
        }
        __syncthreads();
        f32x4 c00 = {0.f,0.f,0.f,0.f}, c01 = {0.f,0.f,0.f,0.f};
        f32x4 c10 = {0.f,0.f,0.f,0.f}, c11 = {0.f,0.f,0.f,0.f};
        #pragma unroll
        for (int kk = 0; kk < 128; kk += 32) {
            short8 a0 = *(const short8*)&As[wr + lr][kk + lk];
            short8 a1 = *(const short8*)&As[wr + 16 + lr][kk + lk];
            short8 b0 = *(const short8*)&Bs[wc + lr][kk + lk];
            short8 b1 = *(const short8*)&Bs[wc + 16 + lr][kk + lk];
            c00 = __builtin_amdgcn_mfma_f32_16x16x32_bf16(a0, b0, c00, 0, 0, 0);
            c01 = __builtin_amdgcn_mfma_f32_16x16x32_bf16(a0, b1, c01, 0, 0, 0);
            c10 = __builtin_amdgcn_mfma_f32_16x16x32_bf16(a1, b0, c10, 0, 0, 0);
            c11 = __builtin_amdgcn_mfma_f32_16x16x32_bf16(a1, b1, c11, 0, 0, 0);
        }
        f32x4 cc[2][2] = {{c00, c01}, {c10, c11}};
        #pragma unroll
        for (int i = 0; i < 2; i++)
            #pragma unroll
            for (int j = 0; j < 2; j++)
                #pragma unroll
                for (int rg = 0; rg < 4; rg++) {
                    int gr = rb + wr + i * 16 + drow + rg;
                    int gc = cb + wc + j * 16 + dcol;
                    if (gr < N_NODES) hr_all[gr * 256 + gc] = f2bf(cc[i][j][rg]);
                }
    }
}

// ---------------- RGCN aggregate: 4 edges/wave, chunked broadcast ----------------
__global__ __launch_bounds__(256) void rgcn_kernel(const unsigned short* __restrict__ hr,
                                                   const float* __restrict__ brg,
                                                   const uint4* __restrict__ bro,
                                                   const unsigned int* __restrict__ ep,
                                                   unsigned short* __restrict__ Hm) {
    int t = threadIdx.x, lane = t & 63;
    int n = blockIdx.x * 4 + (t >> 6);
    if (n >= N_NODES) return;
    int slot = lane >> 4, pos = lane & 15;
    const uint2* H2 = (const uint2*)hr;
    uint4 b = bro[n];
    int p0 = (int)b.x, p1 = (int)b.w;
    int c0 = (int)(b.y - b.x), c1 = (int)(b.z - b.y), c2 = (int)(b.w - b.z);
    float i0 = c0 ? 1.f / (float)c0 : 0.f;
    float i1 = c1 ? 1.f / (float)c1 : 0.f;
    float i2 = c2 ? 1.f / (float)c2 : 0.f;
    f32x2 a01 = {0.f, 0.f}, a23 = {0.f, 0.f};
    for (int base = p0; base < p1; base += 64) {
        int pc = base + lane;
        unsigned chunk = (pc < p1) ? ep[pc] : 0u;
        int cnt = min(64, p1 - base);
        int g0 = 0;
        for (; g0 + 16 <= cnt; g0 += 16) {       // fully valid: no masking
            int i0x = g0 + slot;
            int e0 = __shfl((int)chunk, i0x);
            int e1 = __shfl((int)chunk, i0x + 4);
            int e2 = __shfl((int)chunk, i0x + 8);
            int e3 = __shfl((int)chunk, i0x + 12);
            uint2 h0 = H2[(unsigned)e0 * 16 + pos];
            uint2 h1 = H2[(unsigned)e1 * 16 + pos];
            uint2 h2v = H2[(unsigned)e2 * 16 + pos];
            uint2 h3 = H2[(unsigned)e3 * 16 + pos];
            float w0 = ((e0 & 3) == 0) ? i0 : ((e0 & 3) == 1) ? i1 : i2;
            float w1 = ((e1 & 3) == 0) ? i0 : ((e1 & 3) == 1) ? i1 : i2;
            float w2 = ((e2 & 3) == 0) ? i0 : ((e2 & 3) == 1) ? i1 : i2;
            float w3 = ((e3 & 3) == 0) ? i0 : ((e3 & 3) == 1) ? i1 : i2;
            a01 += w0 * bfpair(h0.x); a23 += w0 * bfpair(h0.y);
            a01 += w1 * bfpair(h1.x); a23 += w1 * bfpair(h1.y);
            a01 += w2 * bfpair(h2v.x); a23 += w2 * bfpair(h2v.y);
            a01 += w3 * bfpair(h3.x); a23 += w3 * bfpair(h3.y);
        }
        for (; g0 < cnt; g0 += 8) {              // remainder: masked via weight
            int iA = g0 + slot, iB = iA + 4;
            int e0 = __shfl((int)chunk, iA);
            int e1 = __shfl((int)chunk, iB);
            uint2 h0 = H2[(unsigned)e0 * 16 + pos];
            uint2 h1 = H2[(unsigned)e1 * 16 + pos];
            float w0 = ((e0 & 3) == 0) ? i0 : ((e0 & 3) == 1) ? i1 : i2;
            float w1 = ((e1 & 3) == 0) ? i0 : ((e1 & 3) == 1) ? i1 : i2;
            w0 = (iA < cnt) ? w0 : 0.f;
            w1 = (iB < cnt) ? w1 : 0.f;
            a01 += w0 * bfpair(h0.x); a23 += w0 * bfpair(h0.y);
            a01 += w1 * bfpair(h1.x); a23 += w1 * bfpair(h1.y);
        }
    }
    a01.x += __shfl_xor(a01.x, 16); a01.x += __shfl_xor(a01.x, 32);
    a01.y += __shfl_xor(a01.y, 16); a01.y += __shfl_xor(a01.y, 32);
    a23.x += __shfl_xor(a23.x, 16); a23.x += __shfl_xor(a23.x, 32);
    a23.y += __shfl_xor(a23.y, 16); a23.y += __shfl_xor(a23.y, 32);
    uint2 rt = H2[(n * 4 + 3) * 16 + pos];   // root block
    f32x2 r01 = bfpair(rt.x), r23 = bfpair(rt.y);
    float4 bb = ((const float4*)brg)[pos];
    float h0 = fmaxf(r01.x + bb.x + a01.x, 0.f);
    float h1 = fmaxf(r01.y + bb.y + a01.y, 0.f);
    float h2s = fmaxf(r23.x + bb.z + a23.x, 0.f);
    float h3 = fmaxf(r23.y + bb.w + a23.y, 0.f);
    if (slot == 0) {
        uint2 wv;
        wv.x = (unsigned)f2bf(h0) | ((unsigned)f2bf(h1) << 16);
        wv.y = (unsigned)f2bf(h2s) | ((unsigned)f2bf(h3) << 16);
        ((uint2*)Hm)[n * 16 + pos] = wv;
    }
}

// ---------------- GEMM2 (MFMA bf16): Hm[N,64] @ W2[64,512] + bcat -> QS,KV (fp16 [N][256] each) ----------------
// QS row: [Q(128, pre-scaled by QSC) | skip(128)] ; KV row: [K(128) | V(128)]
__global__ __launch_bounds__(256) void gemm2_mfma(const unsigned short* __restrict__ Hm,
                                                  const unsigned short* __restrict__ W2t,
                                                  const float* __restrict__ bcat,
                                                  _Float16* __restrict__ QS, _Float16* __restrict__ KV) {
    __shared__ unsigned short As[64][72];
    __shared__ unsigned short Bs[64][72];
    int t = threadIdx.x;
    int rb = blockIdx.x * 64;
    #pragma unroll
    for (int i = 0; i < 2; i++) {
        int lin = t + i * 256;
        int row = lin >> 3;
        int k8 = lin & 7;
        uint4 v = make_uint4(0, 0, 0, 0);
        int gr = rb + row;
        if (gr < N_NODES) v = *(const uint4*)&Hm[gr * 64 + k8 * 8];
        *(uint4*)&As[row][k8 * 8] = v;
    }
    int w = t >> 6, l = t & 63;
    int wr = (w >> 1) * 32, wc = (w & 1) * 32;
    int lr = l & 15, lk = (l >> 4) * 8;
    int drow = (l >> 4) * 4;
    int dcol = l & 15;
    for (int cb8 = 0; cb8 < 8; cb8++) {
        int cb = cb8 * 64;
        float qsc = (cb8 < 2) ? QSC : 1.f;
        __syncthreads();
        #pragma unroll
        for (int i = 0; i < 2; i++) {
            int lin = t + i * 256;
            int n = lin >> 3;
            int k8 = lin & 7;
            *(uint4*)&Bs[n][k8 * 8] = *(const uint4*)&W2t[(cb + n) * 64 + k8 * 8];
        }
        __syncthreads();
        f32x4 c00 = {0.f,0.f,0.f,0.f}, c01 = {0.f,0.f,0.f,0.f};
        f32x4 c10 = {0.f,0.f,0.f,0.f}, c11 = {0.f,0.f,0.f,0.f};
        #pragma unroll
        for (int kk = 0; kk < 64; kk += 32) {
            short8 a0 = *(const short8*)&As[wr + lr][kk + lk];
            short8 a1 = *(const short8*)&As[wr + 16 + lr][kk + lk];
            short8 b0 = *(const short8*)&Bs[wc + lr][kk + lk];
            short8 b1 = *(const short8*)&Bs[wc + 16 + lr][kk + lk];
            c00 = __builtin_amdgcn_mfma_f32_16x16x32_bf16(a0, b0, c00, 0, 0, 0);
            c01 = __builtin_amdgcn_mfma_f32_16x16x32_bf16(a0, b1, c01, 0, 0, 0);
            c10 = __builtin_amdgcn_mfma_f32_16x16x32_bf16(a1, b0, c10, 0, 0, 0);
            c11 = __builtin_amdgcn_mfma_f32_16x16x32_bf16(a1, b1, c11, 0, 0, 0);
        }
        f32x4 cc[2][2] = {{c00, c01}, {c10, c11}};
        #pragma unroll
        for (int i = 0; i < 2; i++)
            #pragma unroll
            for (int j = 0; j < 2; j++)
                #pragma unroll
                for (int rg = 0; rg < 4; rg++) {
                    int gr = rb + wr + i * 16 + drow + rg;
                    int gc = cb + wc + j * 16 + dcol;
                    if (gr >= N_NODES) continue;
                    float v = (cc[i][j][rg] + bcat[gc]) * qsc;
                    _Float16 h = (_Float16)v;
                    if (gc < 128) QS[gr * 256 + gc] = h;
                    else if (gc < 384) KV[gr * 256 + gc - 128] = h;
                    else QS[gr * 256 + gc - 256] = h;
                }
    }
}

// ---------------- fused attention + skip + classifier: 4 edges/wave, fp16 packed (round-7 inner loop) ----------------
__global__ __launch_bounds__(256) void attn_kernel(const _Float16* __restrict__ QS,
                                                   const _Float16* __restrict__ KV,
                                                   const uint4* __restrict__ bro,
                                                   const unsigned int* __restrict__ ep,
                                                   const float* __restrict__ Wf, const float* __restrict__ bfv,
                                                   float* __restrict__ out) {
    int t = threadIdx.x, lane = t & 63;
    int n = blockIdx.x * 4 + (t >> 6);
    if (n >= N_NODES) return;
    int slot = lane >> 4, pos = lane & 15;   // lane covers dims pos*8..pos*8+7 of edge-slot `slot`
    const uint4* KV4 = (const uint4*)KV;
    const uint4* QS4 = (const uint4*)QS;
    uint4 qv = QS4[n * 32 + pos];
    h2 qh[4] = { __builtin_bit_cast(h2, qv.x), __builtin_bit_cast(h2, qv.y),
                 __builtin_bit_cast(h2, qv.z), __builtin_bit_cast(h2, qv.w) };
    h2 o[4] = { h2{0,0}, h2{0,0}, h2{0,0}, h2{0,0} };
    float d = 0.f;
    uint4 bnd = bro[n];
    int p0 = (int)bnd.x, p1 = (int)bnd.w;
    for (int base = p0; base < p1; base += 64) {
        int pc = base + lane;
        unsigned chunk = (pc < p1) ? ep[pc] : 0u;
        int cnt = min(64, p1 - base);
        int g0 = 0;
        for (; g0 + 16 <= cnt; g0 += 16) {      // fully-valid groups: no masking
            int i0 = g0 + slot;
            int e0 = __shfl((int)chunk, i0);
            int e1 = __shfl((int)chunk, i0 + 4);
            int e2 = __shfl((int)chunk, i0 + 8);
            int e3 = __shfl((int)chunk, i0 + 12);
            int b0 = ((e0 >> 2) << 5) + pos;
            int b1 = ((e1 >> 2) << 5) + pos;
            int b2 = ((e2 >> 2) << 5) + pos;
            int b3 = ((e3 >> 2) << 5) + pos;
            uint4 k0 = KV4[b0], v0 = KV4[b0 + 16];
            uint4 k1 = KV4[b1], v1 = KV4[b1 + 16];
            uint4 k2 = KV4[b2], v2 = KV4[b2 + 16];
            uint4 k3 = KV4[b3], v3 = KV4[b3 + 16];
            float d0 = dot8h(qh, k0);
            float d1 = dot8h(qh, k1);
            float d2 = dot8h(qh, k2);
            float d3 = dot8h(qh, k3);
            d0 += __shfl_xor(d0, 1); d1 += __shfl_xor(d1, 1); d2 += __shfl_xor(d2, 1); d3 += __shfl_xor(d3, 1);
            d0 += __shfl_xor(d0, 2); d1 += __shfl_xor(d1, 2); d2 += __shfl_xor(d2, 2); d3 += __shfl_xor(d3, 2);
            float w0 = __builtin_amdgcn_exp2f(d0);
            float w1 = __builtin_amdgcn_exp2f(d1);
            float w2 = __builtin_amdgcn_exp2f(d2);
            float w3 = __builtin_amdgcn_exp2f(d3);
            d += (w0 + w1) + (w2 + w3);
            pv8h(o, w0, v0); pv8h(o, w1, v1); pv8h(o, w2, v2); pv8h(o, w3, v3);
        }
        for (; g0 < cnt; g0 += 8) {             // remainder: masked
            int iA = g0 + slot, iB = iA + 4;
            int e0 = __shfl((int)chunk, iA);
            int e1 = __shfl((int)chunk, iB);
            int b0 = ((e0 >> 2) << 5) + pos;
            int b1 = ((e1 >> 2) << 5) + pos;
            uint4 k0 = KV4[b0], v0 = KV4[b0 + 16];
            uint4 k1 = KV4[b1], v1 = KV4[b1 + 16];
            float d0 = dot8h(qh, k0);
            float d1 = dot8h(qh, k1);
            d0 += __shfl_xor(d0, 1); d1 += __shfl_xor(d1, 1);
            d0 += __shfl_xor(d0, 2); d1 += __shfl_xor(d1, 2);
            float w0 = (iA < cnt) ? __builtin_amdgcn_exp2f(d0) : 0.f;
            float w1 = (iB < cnt) ? __builtin_amdgcn_exp2f(d1) : 0.f;
            d += w0 + w1;
            pv8h(o, w0, v0); pv8h(o, w1, v1);
        }
    }
    // combine the 4 edge-slots
    float of[8];
    #pragma unroll
    for (int i = 0; i < 4; i++) { of[2 * i] = (float)o[i].x; of[2 * i + 1] = (float)o[i].y; }
    d += __shfl_xor(d, 16); d += __shfl_xor(d, 32);
    #pragma unroll
    for (int i = 0; i < 8; i++) { of[i] += __shfl_xor(of[i], 16); of[i] += __shfl_xor(of[i], 32); }
    float inv = (d > 0.f) ? 1.f / d : 0.f;
    uint4 sv = QS4[n * 32 + 16 + pos];
    h2 sh[4] = { __builtin_bit_cast(h2, sv.x), __builtin_bit_cast(h2, sv.y),
                 __builtin_bit_cast(h2, sv.z), __builtin_bit_cast(h2, sv.w) };
    float rf[8];
    #pragma unroll
    for (int i = 0; i < 4; i++) {
        rf[2 * i]     = fmaxf((float)sh[i].x + of[2 * i] * inv, 0.f);
        rf[2 * i + 1] = fmaxf((float)sh[i].y + of[2 * i + 1] * inv, 0.f);
    }
    // classifier: slot s computes classes {s, s+4} over its 8 dims; reduce over 16 lanes
    int base_d = pos * 8;
    int cls1 = (slot < 3) ? slot + 4 : 0;   // slot 3's second class is discarded
    float a0 = 0.f, a1 = 0.f;
    #pragma unroll
    for (int i = 0; i < 8; i++) {
        a0 += rf[i] * Wf[(base_d + i) * 7 + slot];
        a1 += rf[i] * Wf[(base_d + i) * 7 + cls1];
    }
    a0 += __shfl_xor(a0, 1); a1 += __shfl_xor(a1, 1);
    a0 += __shfl_xor(a0, 2); a1 += __shfl_xor(a1, 2);
    a0 += __shfl_xor(a0, 4); a1 += __shfl_xor(a1, 4);
    a0 += __shfl_xor(a0, 8); a1 += __shfl_xor(a1, 8);
    if (pos == 0) {
        out[n * 7 + slot] = a0 + bfv[slot];
        if (slot < 3) out[n * 7 + slot + 4] = a1 + bfv[slot + 4];
    }
}

extern "C" void kernel_launch(void* const* d_in, const int* in_sizes, int n_in,
                              void* d_out, int out_size, void* d_ws, size_t ws_size,
                              hipStream_t stream) {
    const float* x     = (const float*)d_in[0];
    const int*   ei    = (const int*)d_in[2];
    const int*   et    = (const int*)d_in[3];
    const float* Wrel  = (const float*)d_in[4];
    const float* Wroot = (const float*)d_in[5];
    const float* brg   = (const float*)d_in[6];
    const float* Wq    = (const float*)d_in[7];
    const float* bq    = (const float*)d_in[8];
    const float* Wk    = (const float*)d_in[9];
    const float* bk    = (const float*)d_in[10];
    const float* Wv    = (const float*)d_in[11];
    const float* bv    = (const float*)d_in[12];
    const float* Wsk   = (const float*)d_in[13];
    const float* bsk   = (const float*)d_in[14];
    const float* Wf    = (const float*)d_in[15];
    const float* bfv   = (const float*)d_in[16];
    float* out = (float*)d_out;

    // workspace layout (~131 MB):
    //  [0,       51.2M)  hr_all bf16 [N][256] (dead after rgcn); QS fp16 [N][256] overlay
    //  [51.2M,  102.4M)  KV fp16 [N][256]  ([K|V])
    //  [102.4M, 115.2M)  Hm bf16 [N,64]
    //  [115.2M, 121.6M)  ep u32 [E]  (src<<2 | r)
    //  [121.6M, 128.0M)  rank u32 [E] (r<<28 | rank)
    //  [128.0M, 129.6M)  bro uint4 [N]
    //  then cntr (memset) / part / W1t / W2t / bcat
    char* ws = (char*)d_ws;
    unsigned short* hr_all = (unsigned short*)(ws + 0);
    _Float16*       QS     = (_Float16*)(ws + 0);
    _Float16*       KV     = (_Float16*)(ws + 51200000);
    unsigned short* Hm     = (unsigned short*)(ws + 102400000);
    unsigned int*   ep     = (unsigned int*)(ws + 115200000);
    unsigned*       rank   = (unsigned*)(ws + 121600000);
    uint4*          bro    = (uint4*)(ws + 128000000);
    int*            cntr   = (int*)(ws + 129600016);
    int*            part   = (int*)(ws + 130800016);
    unsigned short* W1t    = (unsigned short*)(ws + 130800528);
    unsigned short* W2t    = (unsigned short*)(ws + 130866064);
    float*          bcat   = (float*)(ws + 130931600);

    hipMemsetAsync(cntr, 0, 3 * N_NODES * sizeof(int), stream);

    repack_kernel<<<258, 256, 0, stream>>>(Wrel, Wroot, Wq, Wk, Wv, Wsk, bq, bk, bv, bsk, W1t, W2t, bcat);

    // CSR build by destination (rank+relation packed in hist; scatter has no atomics)
    hist_kernel<<<N_EDGES / 256, 256, 0, stream>>>(ei, et, cntr, rank);
    scanA_kernel<<<98, 256, 0, stream>>>(cntr, part);
    scanC_kernel<<<98, 256, 0, stream>>>(cntr, part, bro);
    scatter_kernel<<<N_EDGES / 256, 256, 0, stream>>>(ei, bro, rank, ep);

    // RGCN
    gemm1_mfma<<<1563, 256, 0, stream>>>(x, W1t, hr_all);
    rgcn_kernel<<<25000, 256, 0, stream>>>(hr_all, brg, bro, ep, Hm);

    // TransformerConv
    gemm2_mfma<<<1563, 256, 0, stream>>>(Hm, W2t, bcat, QS, KV);
    attn_kernel<<<25000, 256, 0, stream>>>(QS, KV, bro, ep, Wf, bfv, out);
}